// Round 11
// baseline (148673.401 us; speedup 1.0000x reference)
//
#include <hip/hip_runtime.h>
#include <float.h>

constexpr int SEQ  = 128;   // sentence length T
constexpr int D    = 256;   // DIM / STATEDIM
constexpr int G    = 1024;  // 4*DIM gate width
constexpr int NREL = 26;    // REL_COUNT + 1
constexpr int NENT = 7;

typedef float v2f __attribute__((ext_vector_type(2)));
typedef float v4f __attribute__((ext_vector_type(4)));

// ---------------------------------------------------------------------------
// Generic strided transpose: out[k*rows + i] = in[i*in_stride + in_off + k]
// ---------------------------------------------------------------------------
__global__ void k_trans(const float* __restrict__ in, float* __restrict__ out,
                        int rows, int cols, int in_stride, int in_off)
{
    int idx = blockIdx.x * 256 + threadIdx.x;
    if (idx >= rows * cols) return;
    int i = idx % rows;
    int k = idx / rows;
    out[idx] = in[(size_t)i * in_stride + in_off + k];
}

// ---------------------------------------------------------------------------
// xg[t][j] = bih[j] + bhh[j] + sum_k wordvector[text[t]][k] * Wih[j][k]
// ---------------------------------------------------------------------------
__global__ __launch_bounds__(1024) void k_xg(
    const int* __restrict__ text, const float* __restrict__ wv,
    const float* __restrict__ Wih, const float* __restrict__ bih,
    const float* __restrict__ bhh, float* __restrict__ xg)
{
    int t = blockIdx.x, j = threadIdx.x;
    const float* x  = wv + (size_t)text[t] * D;
    const float* wr = Wih + (size_t)j * D;
    float acc = bih[j] + bhh[j];
    for (int k = 0; k < D; ++k) acc += x[k] * wr[k];
    xg[t * G + j] = acc;
}

// ---------------------------------------------------------------------------
// Sequential LSTM, one block per direction (grid=2), 1024 threads.
// ---------------------------------------------------------------------------
__global__ __launch_bounds__(1024) void k_lstm(
    const float* __restrict__ xgF, const float* __restrict__ xgB,
    const float* __restrict__ WHTF, const float* __restrict__ WHTB,
    float* __restrict__ wordin)
{
    int dir = blockIdx.x;
    const float* xg  = dir ? xgB  : xgF;
    const float* WHT = dir ? WHTB : WHTF;
    __shared__ float h[D], c[D], g[G];
    int j = threadIdx.x;
    if (j < D) { h[j] = 0.f; c[j] = 0.f; }
    __syncthreads();
    for (int s = 0; s < SEQ; ++s) {
        int t = dir ? (SEQ - 1 - s) : s;
        float acc = xg[t * G + j];
        for (int k = 0; k < D; ++k) acc += WHT[k * G + j] * h[k];
        g[j] = acc;
        __syncthreads();
        if (j < D) {
            float si = 1.f / (1.f + expf(-g[j]));
            float sf = 1.f / (1.f + expf(-g[D + j]));
            float gg = tanhf(g[2 * D + j]);
            float so = 1.f / (1.f + expf(-g[3 * D + j]));
            float cn = sf * c[j] + si * gg;
            float hn = so * tanhf(cn);
            c[j] = cn; h[j] = hn;
            wordin[t * (2 * D) + dir * D + j] = hn;
        }
        __syncthreads();
    }
}

// ---------------------------------------------------------------------------
// Parallel precompute after LSTM (TW/BW per word, RV per relation, EV per ent)
// ---------------------------------------------------------------------------
__global__ __launch_bounds__(256) void k_prep2(
    const float* __restrict__ wordin,
    const float* __restrict__ WTWT, const float* __restrict__ WBWT,
    const float* __restrict__ WTRT, const float* __restrict__ WBET,
    const float* __restrict__ relvec, const float* __restrict__ entvec,
    const float* __restrict__ btv, const float* __restrict__ bbv,
    float* __restrict__ TW, float* __restrict__ BW,
    float* __restrict__ RV, float* __restrict__ EV)
{
    int b = blockIdx.x, i = threadIdx.x;
    if (b < SEQ) {
        const float* w = wordin + b * (2 * D);
        float a1 = btv[i], a2 = bbv[i];
        for (int j = 0; j < 2 * D; ++j) {
            float wv = w[j];
            a1 += wv * WTWT[j * D + i];
            a2 += wv * WBWT[j * D + i];
        }
        TW[b * D + i] = a1;
        BW[b * D + i] = a2;
    } else if (b < SEQ + NREL) {
        int r = b - SEQ;
        const float* x = relvec + r * D;
        float a = 0.f;
        for (int k = 0; k < D; ++k) a += x[k] * WTRT[k * D + i];
        RV[r * D + i] = a;
    } else {
        int e = b - SEQ - NREL;
        const float* x = entvec + e * D;
        float a = 0.f;
        for (int k = 0; k < D; ++k) a += x[k] * WBET[k * D + i];
        EV[e * D + i] = a;
    }
}

// ---------------------------------------------------------------------------
// M1T[j*D + i] = sum_k WBGT[k*D+i] * Wtt[k*D+j]   (M1 = Wb_target @ Wtt)
// ---------------------------------------------------------------------------
__global__ __launch_bounds__(256) void k_m1(
    const float* __restrict__ WBGT, const float* __restrict__ Wtt,
    float* __restrict__ M1T)
{
    int j = blockIdx.x, i = threadIdx.x;
    float a = 0.f;
    for (int k = 0; k < D; ++k) a = fmaf(WBGT[k * D + i], Wtt[k * D + j], a);
    M1T[j * D + i] = a;
}

// c1[i] = sum_k WBGT[k*D+i] * btt[k]
__global__ __launch_bounds__(256) void k_c1(
    const float* __restrict__ WBGT, const float* __restrict__ btt,
    float* __restrict__ c1)
{
    int i = threadIdx.x;
    float a = 0.f;
    for (int k = 0; k < D; ++k) a = fmaf(WBGT[k * D + i], btt[k], a);
    c1[i] = a;
}

// ---------------------------------------------------------------------------
// Full-column pack: WREG[i*256 + k] = Wb[i][768 + k]  (thread i = output i)
// ---------------------------------------------------------------------------
__global__ __launch_bounds__(256) void k_pack10(
    const float* __restrict__ Wb, float* __restrict__ WREG)
{
    int e = blockIdx.x * 256 + threadIdx.x;      // 0..65535
    int i = e >> 8, k = e & 255;
    WREG[e] = Wb[(size_t)i * (5 * D) + 3 * D + k];
}

// ---------------------------------------------------------------------------
// Full-k streamed matvec (top steps): Wcol = W^T[.. *D + i] (k-major, L2),
// x4 = LDS vector as float4 (broadcast reads). 4 independent chains.
// ---------------------------------------------------------------------------
__device__ inline float mv_full(const float* __restrict__ Wcol,
                                const float4* __restrict__ x4)
{
    float a0 = 0.f, a1 = 0.f, a2 = 0.f, a3 = 0.f;
    #pragma unroll 8
    for (int kk = 0; kk < 64; ++kk) {
        float4 xv = x4[kk];
        a0 = fmaf(Wcol[(4 * kk + 0) * D], xv.x, a0);
        a1 = fmaf(Wcol[(4 * kk + 1) * D], xv.y, a1);
        a2 = fmaf(Wcol[(4 * kk + 2) * D], xv.z, a2);
        a3 = fmaf(Wcol[(4 * kk + 3) * D], xv.w, a3);
    }
    return (a0 + a1) + (a2 + a3);
}

// ---------------------------------------------------------------------------
// Softmax + first-occurrence argmax over n values in lanes 0..n-1 of each
// W-lane group (reference-faithful: p = exp(l-max)/sum, argmax over p).
// ---------------------------------------------------------------------------
template<int W>
__device__ inline void grp_smax(float lv, int n, int lane, int& am, float& pm)
{
    float mx = lv;
    #pragma unroll
    for (int off = W / 2; off; off >>= 1) mx = fmaxf(mx, __shfl_xor(mx, off));
    float e  = (lane < n) ? expf(lv - mx) : 0.f;
    float se = e;
    #pragma unroll
    for (int off = W / 2; off; off >>= 1) se += __shfl_xor(se, off);
    float p  = (lane < n) ? (e / se) : -1.f;
    float q  = p;
    #pragma unroll
    for (int off = W / 2; off; off >>= 1) q = fmaxf(q, __shfl_xor(q, off));
    unsigned long long mask = __ballot(p == q);
    am = __ffsll((long long)mask) - 1;
    pm = q;
}

// ---- weight-FMA macros ------------------------------------------------------
// VGPR tier (f4 n, covers x f4 n): accumulate into A0/A1
#define VF(n)                                                                 \
    { v4f xx_ = xb[n];                                                        \
      A0 = __builtin_elementwise_fma((v2f){wv##n.x, wv##n.y},                 \
                                     (v2f){xx_.x, xx_.y}, A0);                \
      A1 = __builtin_elementwise_fma((v2f){wv##n.z, wv##n.w},                 \
                                     (v2f){xx_.z, xx_.w}, A1); }
// AGPR tier (f4 n, covers x f4 32+n): accumulate into A2/A3
#define AF(n)                                                                 \
    { v4f xx_ = xb[32 + n];                                                   \
      A2 = __builtin_elementwise_fma(aw##n##a, (v2f){xx_.x, xx_.y}, A2);      \
      A3 = __builtin_elementwise_fma(aw##n##b, (v2f){xx_.z, xx_.w}, A3); }
#define ALOAD(n, idx)                                                         \
    { v4f t_ = r4[idx];                                                       \
      aw##n##a = (v2f){t_.x, t_.y}; aw##n##b = (v2f){t_.z, t_.w}; }
// batch anchors: force the 16 v2f of one 8-f4 group into AGPR class
#define ANCH(n0,n1,n2,n3,n4,n5,n6,n7)                                         \
    asm volatile("" : "+a"(aw##n0##a), "+a"(aw##n0##b),                       \
                      "+a"(aw##n1##a), "+a"(aw##n1##b),                       \
                      "+a"(aw##n2##a), "+a"(aw##n2##b),                       \
                      "+a"(aw##n3##a), "+a"(aw##n3##b),                       \
                      "+a"(aw##n4##a), "+a"(aw##n4##b),                       \
                      "+a"(aw##n5##a), "+a"(aw##n5##b),                       \
                      "+a"(aw##n6##a), "+a"(aw##n6##b),                       \
                      "+a"(aw##n7##a), "+a"(aw##n7##b));
#define ANCH0 ANCH(0,1,2,3,4,5,6,7)
#define ANCH1 ANCH(8,9,10,11,12,13,14,15)
#define ANCH2 ANCH(16,17,18,19,20,21,22,23)
#define ANCH3 ANCH(24,25,26,27,28,29,30,31)

// ---------------------------------------------------------------------------
// Sequential main kernel: 1 block, 256 threads = 4 waves = 1 wave/SIMD.
// R1-R10 law: the 256-float weight column cannot fit the 256-VGPR CLASS plus
// transients -> every C++-only variant spilled to scratch (GBs of HBM).
// gfx950's wave budget is 512 unified regs (no spill through 450, m08).
// Fix: 32 f4 weights in named VGPRs + 32 f4 in AGPR pairs, pinned into the
// AGPR class with per-step empty `asm volatile("" : "+a"(w))` batch anchors.
// All 256 weight floats register-resident; no LDS/L2 weight tier; light
// sched_barrier fences cap xb-load hoisting (~8 f4 in flight).
// ---------------------------------------------------------------------------
__global__ __launch_bounds__(256)
__attribute__((amdgpu_waves_per_eu(1)))
void k_main9(
    const float* __restrict__ TW,   const float* __restrict__ BW,
    const float* __restrict__ RV,   const float* __restrict__ EV,
    const float* __restrict__ WTMT, const float* __restrict__ WTBT,
    const float* __restrict__ WBTT, const float* __restrict__ M1T,
    const float* __restrict__ c1v,  const float* __restrict__ WREG,
    const float* __restrict__ Wp,   const float* __restrict__ bp,
    const float* __restrict__ Wpl,  const float* __restrict__ bpl,
    const float* __restrict__ btb,  const float* __restrict__ bbt,
    float* __restrict__ out)
{
    const int tid  = threadIdx.x;     // = output index i
    const int lane = tid & 63;
    const int w8   = tid >> 6;        // wave id 0..3

    __shared__ __align__(16) float xbuf[2][D];
    __shared__ __align__(16) float mem[D], outv[D];
    __shared__ __align__(16) float WrSh[NENT * D];
    __shared__ float lpartT[4][32];
    __shared__ float lpartB[2][4][8];
    __shared__ float brSh[8];

    mem[tid] = 0.f;

    const v4f* r4 = reinterpret_cast<const v4f*>(WREG) + tid * 64;

    // VGPR tier: k = 0..127 in 32 named v4f (128 VGPRs)
    v4f wv0 = r4[0],   wv1 = r4[1],   wv2 = r4[2],   wv3 = r4[3];
    v4f wv4 = r4[4],   wv5 = r4[5],   wv6 = r4[6],   wv7 = r4[7];
    v4f wv8 = r4[8],   wv9 = r4[9],   wv10 = r4[10], wv11 = r4[11];
    v4f wv12 = r4[12], wv13 = r4[13], wv14 = r4[14], wv15 = r4[15];
    v4f wv16 = r4[16], wv17 = r4[17], wv18 = r4[18], wv19 = r4[19];
    v4f wv20 = r4[20], wv21 = r4[21], wv22 = r4[22], wv23 = r4[23];
    v4f wv24 = r4[24], wv25 = r4[25], wv26 = r4[26], wv27 = r4[27];
    v4f wv28 = r4[28], wv29 = r4[29], wv30 = r4[30], wv31 = r4[31];

    // AGPR tier: k = 128..255 as 64 v2f pairs (128 AGPRs)
    v2f aw0a,aw0b,aw1a,aw1b,aw2a,aw2b,aw3a,aw3b;
    v2f aw4a,aw4b,aw5a,aw5b,aw6a,aw6b,aw7a,aw7b;
    v2f aw8a,aw8b,aw9a,aw9b,aw10a,aw10b,aw11a,aw11b;
    v2f aw12a,aw12b,aw13a,aw13b,aw14a,aw14b,aw15a,aw15b;
    v2f aw16a,aw16b,aw17a,aw17b,aw18a,aw18b,aw19a,aw19b;
    v2f aw20a,aw20b,aw21a,aw21b,aw22a,aw22b,aw23a,aw23b;
    v2f aw24a,aw24b,aw25a,aw25b,aw26a,aw26b,aw27a,aw27b;
    v2f aw28a,aw28b,aw29a,aw29b,aw30a,aw30b,aw31a,aw31b;
    ALOAD(0,32)  ALOAD(1,33)  ALOAD(2,34)  ALOAD(3,35)
    ALOAD(4,36)  ALOAD(5,37)  ALOAD(6,38)  ALOAD(7,39)
    ALOAD(8,40)  ALOAD(9,41)  ALOAD(10,42) ALOAD(11,43)
    ALOAD(12,44) ALOAD(13,45) ALOAD(14,46) ALOAD(15,47)
    ALOAD(16,48) ALOAD(17,49) ALOAD(18,50) ALOAD(19,51)
    ALOAD(20,52) ALOAD(21,53) ALOAD(22,54) ALOAD(23,55)
    ALOAD(24,56) ALOAD(25,57) ALOAD(26,58) ALOAD(27,59)
    ALOAD(28,60) ALOAD(29,61) ALOAD(30,62) ALOAD(31,63)
    ANCH0 ANCH1 ANCH2 ANCH3       // establish AGPR residence

    // loop-invariant entity columns in registers (7 regs)
    float ev0 = EV[0 * D + tid], ev1 = EV[1 * D + tid], ev2 = EV[2 * D + tid],
          ev3 = EV[3 * D + tid], ev4 = EV[4 * D + tid], ev5 = EV[5 * D + tid],
          ev6 = EV[6 * D + tid];

    __syncthreads();

    const float* WTMc = WTMT + tid;
    const float* WTBc = WTBT + tid;
    const float* WBTc = WBTT + tid;
    const float* M1c  = M1T  + tid;

    int rel = 0;

    for (int t = 0; t < SEQ; ++t) {
        // ---- top step: outp = tanh(TW[t] + RV[rel] + Wt_m @ mem) ----
        float a = mv_full(WTMc, reinterpret_cast<const float4*>(mem));
        float outp = tanhf(a + TW[t * D + tid] + RV[rel * D + tid]);
        outv[tid] = outp;
        for (int r = 0; r < NREL; ++r) {
            float pp = outp * Wp[r * D + tid];
            #pragma unroll
            for (int off = 32; off; off >>= 1) pp += __shfl_xor(pp, off);
            if (lane == 0) lpartT[w8][r] = pp;
        }
        __syncthreads();
        float lv = -FLT_MAX;
        if (lane < NREL)
            lv = lpartT[0][lane] + lpartT[1][lane] + lpartT[2][lane] +
                 lpartT[3][lane] + bp[lane];
        int am; float pm;
        grp_smax<32>(lv, NREL, lane, am, pm);
        if (tid == 0) { out[t] = (float)am; out[SEQ + t] = pm; }
        const int action = am;   // wave-uniform

        if (action > 0) {
            rel = action;
            // memb0 = Wtb@outp + btb ;  btm = M1@outp + c1  (tgt folded away)
            float bs = mv_full(WTBc, reinterpret_cast<const float4*>(outv));
            float cs = mv_full(M1c,  reinterpret_cast<const float4*>(outv));
            const size_t wb0 = (size_t)(action - 1) * NENT * D;
            for (int k = tid; k < NENT * D; k += 256) WrSh[k] = Wpl[wb0 + k];
            if (tid < NENT) brSh[tid] = bpl[(action - 1) * NENT + tid];
            float btm = cs + c1v[tid];
            xbuf[0][tid] = bs + btb[tid];
            float bwc = BW[tid];            // prefetch BW row 0
            __syncthreads();

            int p = 0, ab = 0;
            for (int s = 0; s < SEQ; ++s) {
                const v4f* xb = reinterpret_cast<const v4f*>(xbuf[p]);
                v2f A0 = {0.f, 0.f}, A1 = {0.f, 0.f},
                    A2 = {0.f, 0.f}, A3 = {0.f, 0.f};
                // VGPR tier k=0..127, fenced in 8-f4 batches
                VF(0)  VF(1)  VF(2)  VF(3)  VF(4)  VF(5)  VF(6)  VF(7)
                __builtin_amdgcn_sched_barrier(0);
                VF(8)  VF(9)  VF(10) VF(11) VF(12) VF(13) VF(14) VF(15)
                __builtin_amdgcn_sched_barrier(0);
                VF(16) VF(17) VF(18) VF(19) VF(20) VF(21) VF(22) VF(23)
                __builtin_amdgcn_sched_barrier(0);
                VF(24) VF(25) VF(26) VF(27) VF(28) VF(29) VF(30) VF(31)
                __builtin_amdgcn_sched_barrier(0);
                // AGPR tier k=128..255, anchored per batch
                ANCH0
                AF(0)  AF(1)  AF(2)  AF(3)  AF(4)  AF(5)  AF(6)  AF(7)
                __builtin_amdgcn_sched_barrier(0);
                ANCH1
                AF(8)  AF(9)  AF(10) AF(11) AF(12) AF(13) AF(14) AF(15)
                __builtin_amdgcn_sched_barrier(0);
                ANCH2
                AF(16) AF(17) AF(18) AF(19) AF(20) AF(21) AF(22) AF(23)
                __builtin_amdgcn_sched_barrier(0);
                ANCH3
                AF(24) AF(25) AF(26) AF(27) AF(28) AF(29) AF(30) AF(31)
                v2f AS = (A0 + A1) + (A2 + A3);
                float ms = AS.x + AS.y;

                float ev = (ab == 0) ? ev0 : (ab == 1) ? ev1 :
                           (ab == 2) ? ev2 : (ab == 3) ? ev3 :
                           (ab == 4) ? ev4 : (ab == 5) ? ev5 : ev6;
                float ob = tanhf(ms + bwc + ev + btm);
                xbuf[p ^ 1][tid] = ob;
                #pragma unroll
                for (int r = 0; r < NENT; ++r) {
                    float pp = ob * WrSh[r * D + tid];
                    #pragma unroll
                    for (int off = 32; off; off >>= 1)
                        pp += __shfl_xor(pp, off);
                    if (lane == 0) lpartB[p][w8][r] = pp;
                }
                __syncthreads();                      // the ONE barrier/step
                float lv2 = -FLT_MAX;
                if (lane < NENT)
                    lv2 = lpartB[p][0][lane] + lpartB[p][1][lane] +
                          lpartB[p][2][lane] + lpartB[p][3][lane] + brSh[lane];
                int am2; float pm2;
                grp_smax<8>(lv2, NENT, lane, am2, pm2);
                if (tid == 0) {
                    out[2 * SEQ + t * SEQ + s] = (float)am2;
                    out[2 * SEQ + SEQ * SEQ + t * SEQ + s] = pm2;
                }
                ab = am2;
                int sn = (s + 1 < SEQ) ? s + 1 : s;
                bwc = BW[sn * D + tid];               // prefetch next row
                p ^= 1;
            }
            // mem = Wbt @ membf + bbt
            float es = mv_full(WBTc, reinterpret_cast<const float4*>(xbuf[p]));
            mem[tid] = es + bbt[tid];
            __syncthreads();
        } else {
            mem[tid] = outp;
            if (tid < SEQ) {
                out[2 * SEQ + t * SEQ + tid] = 0.f;
                out[2 * SEQ + SEQ * SEQ + t * SEQ + tid] = 0.f;
            }
            __syncthreads();
        }
    }
}

// ---------------------------------------------------------------------------
extern "C" void kernel_launch(void* const* d_in, const int* in_sizes, int n_in,
                              void* d_out, int out_size, void* d_ws, size_t ws_size,
                              hipStream_t stream)
{
    (void)in_sizes; (void)n_in; (void)out_size; (void)ws_size;
    const int*   text       = (const int*)  d_in[0];
    const float* wordvector = (const float*)d_in[1];
    const float* relvec     = (const float*)d_in[2];
    const float* entvec     = (const float*)d_in[3];
    const float* WihL = (const float*)d_in[4];  const float* WhhL = (const float*)d_in[5];
    const float* bihL = (const float*)d_in[6];  const float* bhhL = (const float*)d_in[7];
    const float* WihR = (const float*)d_in[8];  const float* WhhR = (const float*)d_in[9];
    const float* bihR = (const float*)d_in[10]; const float* bhhR = (const float*)d_in[11];
    const float* Wt   = (const float*)d_in[12]; const float* bt   = (const float*)d_in[13];
    const float* Wp   = (const float*)d_in[14]; const float* bp   = (const float*)d_in[15];
    const float* Wb   = (const float*)d_in[16]; const float* bb   = (const float*)d_in[17];
    const float* Wpl  = (const float*)d_in[18]; const float* bpl  = (const float*)d_in[19];
    const float* Wtt  = (const float*)d_in[20]; const float* btt  = (const float*)d_in[21];
    const float* Wtb  = (const float*)d_in[22]; const float* btb  = (const float*)d_in[23];
    const float* Wbt  = (const float*)d_in[24]; const float* bbt  = (const float*)d_in[25];

    float* ws = (float*)d_ws;
    size_t o = 0;
    auto take = [&](size_t n) { float* p = ws + o; o += n; return p; };
    float* XGF    = take(SEQ * G);
    float* XGB    = take(SEQ * G);
    float* WHLT   = take(D * G);
    float* WHRT   = take(D * G);
    float* WORDIN = take(SEQ * 2 * D);
    float* TW     = take(SEQ * D);
    float* BW     = take(SEQ * D);
    float* RVb    = take(NREL * D);
    float* EVb    = take(NENT * D);
    float* WTWT   = take(2 * D * D);
    float* WTRT   = take(D * D);
    float* WTMT   = take(D * D);
    float* WBWT   = take(2 * D * D);
    float* WBET   = take(D * D);
    float* WBGT   = take(D * D);
    float* WTBT   = take(D * D);
    float* WBTT   = take(D * D);
    float* M1T    = take(D * D);
    float* C1     = take(D);
    float* WREG   = take(256 * 256);     // full weight column per thread

    auto tr = [&](const float* in, float* outp, int rows, int cols, int stride, int off) {
        int n = rows * cols;
        k_trans<<<(n + 255) / 256, 256, 0, stream>>>(in, outp, rows, cols, stride, off);
    };
    tr(WhhL, WHLT, G, D, D, 0);          // WHLT[k*G + j] = WhhL[j][k]
    tr(WhhR, WHRT, G, D, D, 0);
    tr(Wt,  WTWT, D, 2 * D, G, 0);       // word part of Wt
    tr(Wt,  WTRT, D, D, G, 512);         // relvec part
    tr(Wt,  WTMT, D, D, G, 768);         // mem part
    tr(Wb,  WBWT, D, 2 * D, 5 * D, 0);   // word part of Wb
    tr(Wb,  WBET, D, D, 5 * D, 512);     // entvec part
    tr(Wb,  WBGT, D, D, 5 * D, 1024);    // target part (feeds M1/c1)
    tr(Wtb, WTBT, D, D, D, 0);
    tr(Wbt, WBTT, D, D, D, 0);

    k_m1<<<D, D, 0, stream>>>(WBGT, Wtt, M1T);
    k_c1<<<1, D, 0, stream>>>(WBGT, btt, C1);
    k_pack10<<<256, 256, 0, stream>>>(Wb, WREG);

    k_xg<<<SEQ, 1024, 0, stream>>>(text, wordvector, WihL, bihL, bhhL, XGF);
    k_xg<<<SEQ, 1024, 0, stream>>>(text, wordvector, WihR, bihR, bhhR, XGB);
    k_lstm<<<2, 1024, 0, stream>>>(XGF, XGB, WHLT, WHRT, WORDIN);
    k_prep2<<<SEQ + NREL + NENT, 256, 0, stream>>>(WORDIN, WTWT, WBWT, WTRT, WBET,
                                                   relvec, entvec, bt, bb,
                                                   TW, BW, RVb, EVb);
    k_main9<<<1, 256, 0, stream>>>(TW, BW, RVb, EVb, WTMT, WTBT, WBTT, M1T, C1,
                                   WREG, Wp, bp, Wpl, bpl, btb, bbt,
                                   (float*)d_out);
}

// Round 12
// 61707.660 us; speedup vs baseline: 2.4093x; 2.4093x over previous
//
#include <hip/hip_runtime.h>
#include <float.h>

constexpr int SEQ  = 128;   // sentence length T
constexpr int D    = 256;   // DIM / STATEDIM
constexpr int G    = 1024;  // 4*DIM gate width
constexpr int NREL = 26;    // REL_COUNT + 1
constexpr int NENT = 7;

typedef float v2f __attribute__((ext_vector_type(2)));
typedef float v4f __attribute__((ext_vector_type(4)));

// ---------------------------------------------------------------------------
// Generic strided transpose: out[k*rows + i] = in[i*in_stride + in_off + k]
// ---------------------------------------------------------------------------
__global__ void k_trans(const float* __restrict__ in, float* __restrict__ out,
                        int rows, int cols, int in_stride, int in_off)
{
    int idx = blockIdx.x * 256 + threadIdx.x;
    if (idx >= rows * cols) return;
    int i = idx % rows;
    int k = idx / rows;
    out[idx] = in[(size_t)i * in_stride + in_off + k];
}

// ---------------------------------------------------------------------------
// xg[t][j] = bih[j] + bhh[j] + sum_k wordvector[text[t]][k] * Wih[j][k]
// ---------------------------------------------------------------------------
__global__ __launch_bounds__(1024) void k_xg(
    const int* __restrict__ text, const float* __restrict__ wv,
    const float* __restrict__ Wih, const float* __restrict__ bih,
    const float* __restrict__ bhh, float* __restrict__ xg)
{
    int t = blockIdx.x, j = threadIdx.x;
    const float* x  = wv + (size_t)text[t] * D;
    const float* wr = Wih + (size_t)j * D;
    float acc = bih[j] + bhh[j];
    for (int k = 0; k < D; ++k) acc += x[k] * wr[k];
    xg[t * G + j] = acc;
}

// ---------------------------------------------------------------------------
// Sequential LSTM, one block per direction (grid=2), 1024 threads.
// ---------------------------------------------------------------------------
__global__ __launch_bounds__(1024) void k_lstm(
    const float* __restrict__ xgF, const float* __restrict__ xgB,
    const float* __restrict__ WHTF, const float* __restrict__ WHTB,
    float* __restrict__ wordin)
{
    int dir = blockIdx.x;
    const float* xg  = dir ? xgB  : xgF;
    const float* WHT = dir ? WHTB : WHTF;
    __shared__ float h[D], c[D], g[G];
    int j = threadIdx.x;
    if (j < D) { h[j] = 0.f; c[j] = 0.f; }
    __syncthreads();
    for (int s = 0; s < SEQ; ++s) {
        int t = dir ? (SEQ - 1 - s) : s;
        float acc = xg[t * G + j];
        for (int k = 0; k < D; ++k) acc += WHT[k * G + j] * h[k];
        g[j] = acc;
        __syncthreads();
        if (j < D) {
            float si = 1.f / (1.f + expf(-g[j]));
            float sf = 1.f / (1.f + expf(-g[D + j]));
            float gg = tanhf(g[2 * D + j]);
            float so = 1.f / (1.f + expf(-g[3 * D + j]));
            float cn = sf * c[j] + si * gg;
            float hn = so * tanhf(cn);
            c[j] = cn; h[j] = hn;
            wordin[t * (2 * D) + dir * D + j] = hn;
        }
        __syncthreads();
    }
}

// ---------------------------------------------------------------------------
// Parallel precompute after LSTM (TW/BW per word, RV per relation, EV per ent)
// ---------------------------------------------------------------------------
__global__ __launch_bounds__(256) void k_prep2(
    const float* __restrict__ wordin,
    const float* __restrict__ WTWT, const float* __restrict__ WBWT,
    const float* __restrict__ WTRT, const float* __restrict__ WBET,
    const float* __restrict__ relvec, const float* __restrict__ entvec,
    const float* __restrict__ btv, const float* __restrict__ bbv,
    float* __restrict__ TW, float* __restrict__ BW,
    float* __restrict__ RV, float* __restrict__ EV)
{
    int b = blockIdx.x, i = threadIdx.x;
    if (b < SEQ) {
        const float* w = wordin + b * (2 * D);
        float a1 = btv[i], a2 = bbv[i];
        for (int j = 0; j < 2 * D; ++j) {
            float wv = w[j];
            a1 += wv * WTWT[j * D + i];
            a2 += wv * WBWT[j * D + i];
        }
        TW[b * D + i] = a1;
        BW[b * D + i] = a2;
    } else if (b < SEQ + NREL) {
        int r = b - SEQ;
        const float* x = relvec + r * D;
        float a = 0.f;
        for (int k = 0; k < D; ++k) a += x[k] * WTRT[k * D + i];
        RV[r * D + i] = a;
    } else {
        int e = b - SEQ - NREL;
        const float* x = entvec + e * D;
        float a = 0.f;
        for (int k = 0; k < D; ++k) a += x[k] * WBET[k * D + i];
        EV[e * D + i] = a;
    }
}

// ---------------------------------------------------------------------------
// M1T[j*D + i] = sum_k WBGT[k*D+i] * Wtt[k*D+j]   (M1 = Wb_target @ Wtt)
// ---------------------------------------------------------------------------
__global__ __launch_bounds__(256) void k_m1(
    const float* __restrict__ WBGT, const float* __restrict__ Wtt,
    float* __restrict__ M1T)
{
    int j = blockIdx.x, i = threadIdx.x;
    float a = 0.f;
    for (int k = 0; k < D; ++k) a = fmaf(WBGT[k * D + i], Wtt[k * D + j], a);
    M1T[j * D + i] = a;
}

// c1[i] = sum_k WBGT[k*D+i] * btt[k]
__global__ __launch_bounds__(256) void k_c1(
    const float* __restrict__ WBGT, const float* __restrict__ btt,
    float* __restrict__ c1)
{
    int i = threadIdx.x;
    float a = 0.f;
    for (int k = 0; k < D; ++k) a = fmaf(WBGT[k * D + i], btt[k], a);
    c1[i] = a;
}

// ---------------------------------------------------------------------------
// Packs for the 2-tier bot weight matvec (512 threads, tid = h*256+i):
//  reg tier  q=0..55  : WREG[tid*56 + q]        = Wb[i][768 + h*128 + q]
//  LDS tier  j=0..17  : f4 slot (w*18+j)*64 + l = thread (w*64+l)'s j-th f4
//                        = Wb[i][768 + h*128 + 56 + 4j + c]
// ---------------------------------------------------------------------------
__global__ __launch_bounds__(256) void k_packAr(
    const float* __restrict__ Wb, float* __restrict__ WREG)
{
    int e = blockIdx.x * 256 + threadIdx.x;      // 0..28671
    if (e >= 512 * 56) return;
    int tid = e / 56, q = e % 56;
    int h = tid >> 8, i = tid & 255;
    WREG[e] = Wb[(size_t)i * (5 * D) + 3 * D + h * 128 + q];
}

__global__ __launch_bounds__(256) void k_packAl(
    const float* __restrict__ Wb, float* __restrict__ WLDS)
{
    int f = blockIdx.x * 256 + threadIdx.x;      // 0..36863
    if (f >= 512 * 72) return;
    int f4 = f >> 2, c = f & 3;
    int l = f4 & 63, rest = f4 >> 6;
    int j = rest % 18, w = rest / 18;
    int tid = w * 64 + l;
    int h = tid >> 8, i = tid & 255;
    WLDS[f] = Wb[(size_t)i * (5 * D) + 3 * D + h * 128 + 56 + 4 * j + c];
}

// ---------------------------------------------------------------------------
// Streamed split-k half-matvec (top steps): Wcol = W^T[k0*D + i] (k-major),
// x = LDS vector slice for this k-half (128 elements). 4 independent chains.
// ---------------------------------------------------------------------------
__device__ inline float mv_half(const float* __restrict__ Wcol,
                                const float* __restrict__ x)
{
    float a0 = 0.f, a1 = 0.f, a2 = 0.f, a3 = 0.f;
    #pragma unroll
    for (int kk = 0; kk < 128; kk += 4) {
        a0 = fmaf(Wcol[(kk + 0) * D], x[kk + 0], a0);
        a1 = fmaf(Wcol[(kk + 1) * D], x[kk + 1], a1);
        a2 = fmaf(Wcol[(kk + 2) * D], x[kk + 2], a2);
        a3 = fmaf(Wcol[(kk + 3) * D], x[kk + 3], a3);
    }
    return (a0 + a1) + (a2 + a3);
}

// ---------------------------------------------------------------------------
// Softmax + first-occurrence argmax over n values in lanes 0..n-1 of each
// W-lane group (reference-faithful: p = exp(l-max)/sum, argmax over p).
// ---------------------------------------------------------------------------
template<int W>
__device__ inline void grp_smax(float lv, int n, int lane, int& am, float& pm)
{
    float mx = lv;
    #pragma unroll
    for (int off = W / 2; off; off >>= 1) mx = fmaxf(mx, __shfl_xor(mx, off));
    float e  = (lane < n) ? expf(lv - mx) : 0.f;
    float se = e;
    #pragma unroll
    for (int off = W / 2; off; off >>= 1) se += __shfl_xor(se, off);
    float p  = (lane < n) ? (e / se) : -1.f;
    float q  = p;
    #pragma unroll
    for (int off = W / 2; off; off >>= 1) q = fmaxf(q, __shfl_xor(q, off));
    unsigned long long mask = __ballot(p == q);
    am = __ffsll((long long)mask) - 1;
    pm = q;
}

// FMA helpers: one float4 pair into two v2f accumulators
#define FMA_AB(Wv, Xv)                                                        \
    { v4f xx_ = (Xv);                                                         \
      A0 = __builtin_elementwise_fma((v2f){(Wv).x, (Wv).y},                   \
                                     (v2f){xx_.x, xx_.y}, A0);                \
      A1 = __builtin_elementwise_fma((v2f){(Wv).z, (Wv).w},                   \
                                     (v2f){xx_.z, xx_.w}, A1); }
#define FMA_CD(Wv, Xv)                                                        \
    { v4f xx_ = (Xv);                                                         \
      A2 = __builtin_elementwise_fma((v2f){(Wv).x, (Wv).y},                   \
                                     (v2f){xx_.x, xx_.y}, A2);                \
      A3 = __builtin_elementwise_fma((v2f){(Wv).z, (Wv).w},                   \
                                     (v2f){xx_.z, xx_.w}, A3); }

// one LDS weight chunk: 4 f4 weights x 4 f4 x-broadcast, then a fence
#define LC(j0)                                                                \
    { v4f la = wbase[(j0 + 0) * 64], lb = wbase[(j0 + 1) * 64],               \
          lc = wbase[(j0 + 2) * 64], ld = wbase[(j0 + 3) * 64];               \
      FMA_AB(la, xb[14 + j0 + 0]) FMA_CD(lb, xb[14 + j0 + 1])                 \
      FMA_AB(lc, xb[14 + j0 + 2]) FMA_CD(ld, xb[14 + j0 + 3])                 \
      __builtin_amdgcn_sched_barrier(0); }

// ---------------------------------------------------------------------------
// Sequential main kernel: 1 block, 512 threads = 8 waves = 2 waves/SIMD.
// R1-R11 ledger: (a) weight-register demand above the grant (128 @ 512thr)
// always spills; (b) runtime tracks serialized latency, not FETCH — so the
// fix needs BOTH no-spill AND TLP. Design: 56 weight floats in 14 named f4
// (reg) + 72 floats in LDS (147 KB, conflict-free wave-contiguous layout).
// Peak live ~113 < 128: transients capped by sched_barrier fences every
// 4-f4 chunk AND `#pragma unroll 1` on the s-loop (the p^=1 ping-pong
// otherwise invites a 2x unroll that doubles pressure — R7/R8's killer).
// ---------------------------------------------------------------------------
__global__ __launch_bounds__(512)
void k_mainA(
    const float* __restrict__ TW,   const float* __restrict__ BW,
    const float* __restrict__ RV,   const float* __restrict__ EV,
    const float* __restrict__ WTMT, const float* __restrict__ WTBT,
    const float* __restrict__ WBTT, const float* __restrict__ M1T,
    const float* __restrict__ c1v,  const float* __restrict__ WREG,
    const float* __restrict__ WLDS,
    const float* __restrict__ Wp,   const float* __restrict__ bp,
    const float* __restrict__ Wpl,  const float* __restrict__ bpl,
    const float* __restrict__ btb,  const float* __restrict__ bbt,
    float* __restrict__ out)
{
    const int tid  = threadIdx.x;
    const int lane = tid & 63;
    const int wv8  = tid >> 6;        // wave id 0..7
    const int lwv  = wv8 & 3;         // wave id within half
    const int h    = tid >> 8;        // k-half 0..1
    const int i    = tid & 255;       // output index
    const bool lower = (tid < 256);

    // --- LDS (161,312 B total) ---
    __shared__ __align__(16) float wlds[512 * 72];        // 147,456 B
    __shared__ __align__(16) float xbuf[2][D];            //   2,048 B
    __shared__ __align__(16) float psA[2][D];             //   2,048 B
    __shared__ __align__(16) float mem[D], outv[D];       //   2,048 B
    __shared__ __align__(16) float WrSh[NENT * D];        //   7,168 B
    __shared__ float lpart[4][32];                        //     512 B
    __shared__ float brSh[8];                             //      32 B

    // stage LDS weight tier (pre-packed in exact LDS layout)
    {
        const float4* g4 = reinterpret_cast<const float4*>(WLDS);
        float4* w4 = reinterpret_cast<float4*>(wlds);
        #pragma unroll
        for (int it = 0; it < 18; ++it) w4[tid + it * 512] = g4[tid + it * 512];
    }

    // register tier: 14 NAMED float4 (56 VGPRs)
    const v4f* r4 = reinterpret_cast<const v4f*>(WREG) + tid * 14;
    v4f wr0 = r4[0],   wr1 = r4[1],   wr2 = r4[2],   wr3 = r4[3];
    v4f wr4 = r4[4],   wr5 = r4[5],   wr6 = r4[6],   wr7 = r4[7];
    v4f wr8 = r4[8],   wr9 = r4[9],   wr10 = r4[10], wr11 = r4[11];
    v4f wr12 = r4[12], wr13 = r4[13];

    // loop-invariant entity columns in registers (7 regs)
    float ev0 = EV[0 * D + i], ev1 = EV[1 * D + i], ev2 = EV[2 * D + i],
          ev3 = EV[3 * D + i], ev4 = EV[4 * D + i], ev5 = EV[5 * D + i],
          ev6 = EV[6 * D + i];
    if (lower) mem[i] = 0.f;
    __syncthreads();

    const v4f* wbase =
        reinterpret_cast<const v4f*>(wlds) + (size_t)wv8 * (18 * 64) + lane;

    const float* WTMh = WTMT + (size_t)h * 128 * D + i;
    const float* WTBh = WTBT + (size_t)h * 128 * D + i;
    const float* WBTh = WBTT + (size_t)h * 128 * D + i;
    const float* M1h  = M1T  + (size_t)h * 128 * D + i;

    int rel = 0;

    #pragma unroll 1
    for (int t = 0; t < SEQ; ++t) {
        // ---- top step: outp = tanh(TW[t] + RV[rel] + Wt_m @ mem) ----
        psA[h][i] = mv_half(WTMh, mem + h * 128);
        __syncthreads();
        if (lower) {
            float tot = psA[0][i] + psA[1][i] +
                        TW[t * D + i] + RV[rel * D + i];
            float outp = tanhf(tot);
            outv[i] = outp;
            #pragma unroll 2
            for (int r = 0; r < NREL; ++r) {
                float pp = outp * Wp[r * D + i];
                #pragma unroll
                for (int off = 32; off; off >>= 1) pp += __shfl_xor(pp, off);
                if (lane == 0) lpart[lwv][r] = pp;
            }
        }
        __syncthreads();
        float lv = -FLT_MAX;
        if (lane < NREL)
            lv = lpart[0][lane] + lpart[1][lane] + lpart[2][lane] +
                 lpart[3][lane] + bp[lane];
        int am; float pm;
        grp_smax<32>(lv, NREL, lane, am, pm);
        if (tid == 0) { out[t] = (float)am; out[SEQ + t] = pm; }
        const int action = am;   // wave-uniform

        if (action > 0) {
            rel = action;
            // memb0 = Wtb@outp + btb  (psA reused; extra barriers, top only)
            psA[h][i] = mv_half(WTBh, outv + h * 128);
            const size_t wb0 = (size_t)(action - 1) * NENT * D;
            for (int k = tid; k < NENT * D; k += 512) WrSh[k] = Wpl[wb0 + k];
            if (tid < NENT) brSh[tid] = bpl[(action - 1) * NENT + tid];
            __syncthreads();
            if (lower) xbuf[0][i] = psA[0][i] + psA[1][i] + btb[i];
            __syncthreads();
            // btm = M1@outp + c1  (tgt matvec folded away)
            psA[h][i] = mv_half(M1h, outv + h * 128);
            __syncthreads();
            float btm = 0.f, bwc = 0.f;
            if (lower) {
                btm = psA[0][i] + psA[1][i] + c1v[i];
                bwc = BW[i];          // prefetch BW row 0
            }
            __syncthreads();

            int p = 0, ab = 0;
            #pragma unroll 1
            for (int s = 0; s < SEQ; ++s) {
                // -- half-matvec: 56 k from named VGPRs + 72 k from LDS --
                const v4f* xb = reinterpret_cast<const v4f*>(xbuf[p] + h * 128);
                v2f A0 = {0.f, 0.f}, A1 = {0.f, 0.f},
                    A2 = {0.f, 0.f}, A3 = {0.f, 0.f};
                FMA_AB(wr0,  xb[0])  FMA_CD(wr1,  xb[1])
                FMA_AB(wr2,  xb[2])  FMA_CD(wr3,  xb[3])
                __builtin_amdgcn_sched_barrier(0);
                FMA_AB(wr4,  xb[4])  FMA_CD(wr5,  xb[5])
                FMA_AB(wr6,  xb[6])  FMA_CD(wr7,  xb[7])
                __builtin_amdgcn_sched_barrier(0);
                FMA_AB(wr8,  xb[8])  FMA_CD(wr9,  xb[9])
                FMA_AB(wr10, xb[10]) FMA_CD(wr11, xb[11])
                __builtin_amdgcn_sched_barrier(0);
                FMA_AB(wr12, xb[12]) FMA_CD(wr13, xb[13])
                __builtin_amdgcn_sched_barrier(0);
                LC(0) LC(4) LC(8) LC(12)
                { v4f la = wbase[16 * 64], lb = wbase[17 * 64];
                  FMA_AB(la, xb[30]) FMA_CD(lb, xb[31]) }
                v2f AS = (A0 + A1) + (A2 + A3);
                float ms = AS.x + AS.y;
                psA[h][i] = ms;
                __syncthreads();                       // barrier 1
                if (lower) {
                    float ev = (ab == 0) ? ev0 : (ab == 1) ? ev1 :
                               (ab == 2) ? ev2 : (ab == 3) ? ev3 :
                               (ab == 4) ? ev4 : (ab == 5) ? ev5 : ev6;
                    float tot = ms + psA[1][i] + bwc + ev + btm;
                    float ob = tanhf(tot);
                    xbuf[p ^ 1][i] = ob;
                    #pragma unroll
                    for (int r = 0; r < NENT; ++r) {
                        float pp = ob * WrSh[r * D + i];
                        #pragma unroll
                        for (int off = 32; off; off >>= 1)
                            pp += __shfl_xor(pp, off);
                        if (lane == 0) lpart[lwv][r] = pp;
                    }
                    int sn = (s + 1 < SEQ) ? s + 1 : s;
                    bwc = BW[sn * D + i];              // prefetch next row
                }
                __syncthreads();                       // barrier 2
                float lv2 = -FLT_MAX;
                if (lane < NENT)
                    lv2 = lpart[0][lane] + lpart[1][lane] + lpart[2][lane] +
                          lpart[3][lane] + brSh[lane];
                int am2; float pm2;
                grp_smax<8>(lv2, NENT, lane, am2, pm2);
                if (tid == 0) {
                    out[2 * SEQ + t * SEQ + s] = (float)am2;
                    out[2 * SEQ + SEQ * SEQ + t * SEQ + s] = pm2;
                }
                ab = am2;        // wave-uniform register, no LDS roundtrip
                p ^= 1;
            }
            // mem = Wbt @ membf + bbt
            psA[h][i] = mv_half(WBTh, xbuf[p] + h * 128);
            __syncthreads();
            if (lower) mem[i] = psA[0][i] + psA[1][i] + bbt[i];
            __syncthreads();
        } else {
            if (lower) mem[i] = outv[i];
            if (tid < SEQ) {
                out[2 * SEQ + t * SEQ + tid] = 0.f;
                out[2 * SEQ + SEQ * SEQ + t * SEQ + tid] = 0.f;
            }
            __syncthreads();
        }
    }
}

// ---------------------------------------------------------------------------
extern "C" void kernel_launch(void* const* d_in, const int* in_sizes, int n_in,
                              void* d_out, int out_size, void* d_ws, size_t ws_size,
                              hipStream_t stream)
{
    (void)in_sizes; (void)n_in; (void)out_size; (void)ws_size;
    const int*   text       = (const int*)  d_in[0];
    const float* wordvector = (const float*)d_in[1];
    const float* relvec     = (const float*)d_in[2];
    const float* entvec     = (const float*)d_in[3];
    const float* WihL = (const float*)d_in[4];  const float* WhhL = (const float*)d_in[5];
    const float* bihL = (const float*)d_in[6];  const float* bhhL = (const float*)d_in[7];
    const float* WihR = (const float*)d_in[8];  const float* WhhR = (const float*)d_in[9];
    const float* bihR = (const float*)d_in[10]; const float* bhhR = (const float*)d_in[11];
    const float* Wt   = (const float*)d_in[12]; const float* bt   = (const float*)d_in[13];
    const float* Wp   = (const float*)d_in[14]; const float* bp   = (const float*)d_in[15];
    const float* Wb   = (const float*)d_in[16]; const float* bb   = (const float*)d_in[17];
    const float* Wpl  = (const float*)d_in[18]; const float* bpl  = (const float*)d_in[19];
    const float* Wtt  = (const float*)d_in[20]; const float* btt  = (const float*)d_in[21];
    const float* Wtb  = (const float*)d_in[22]; const float* btb  = (const float*)d_in[23];
    const float* Wbt  = (const float*)d_in[24]; const float* bbt  = (const float*)d_in[25];

    float* ws = (float*)d_ws;
    size_t o = 0;
    auto take = [&](size_t n) { float* p = ws + o; o += n; return p; };
    float* XGF    = take(SEQ * G);
    float* XGB    = take(SEQ * G);
    float* WHLT   = take(D * G);
    float* WHRT   = take(D * G);
    float* WORDIN = take(SEQ * 2 * D);
    float* TW     = take(SEQ * D);
    float* BW     = take(SEQ * D);
    float* RVb    = take(NREL * D);
    float* EVb    = take(NENT * D);
    float* WTWT   = take(2 * D * D);
    float* WTRT   = take(D * D);
    float* WTMT   = take(D * D);
    float* WBWT   = take(2 * D * D);
    float* WBET   = take(D * D);
    float* WBGT   = take(D * D);
    float* WTBT   = take(D * D);
    float* WBTT   = take(D * D);
    float* M1T    = take(D * D);
    float* C1     = take(D);
    float* WREG   = take(512 * 56);      // register-tier pack
    float* WLDS   = take(512 * 72);      // LDS-tier pack (LDS layout order)

    auto tr = [&](const float* in, float* outp, int rows, int cols, int stride, int off) {
        int n = rows * cols;
        k_trans<<<(n + 255) / 256, 256, 0, stream>>>(in, outp, rows, cols, stride, off);
    };
    tr(WhhL, WHLT, G, D, D, 0);          // WHLT[k*G + j] = WhhL[j][k]
    tr(WhhR, WHRT, G, D, D, 0);
    tr(Wt,  WTWT, D, 2 * D, G, 0);       // word part of Wt
    tr(Wt,  WTRT, D, D, G, 512);         // relvec part
    tr(Wt,  WTMT, D, D, G, 768);         // mem part
    tr(Wb,  WBWT, D, 2 * D, 5 * D, 0);   // word part of Wb
    tr(Wb,  WBET, D, D, 5 * D, 512);     // entvec part
    tr(Wb,  WBGT, D, D, 5 * D, 1024);    // target part (feeds M1/c1)
    tr(Wtb, WTBT, D, D, D, 0);
    tr(Wbt, WBTT, D, D, D, 0);

    k_m1<<<D, D, 0, stream>>>(WBGT, Wtt, M1T);
    k_c1<<<1, D, 0, stream>>>(WBGT, btt, C1);
    k_packAr<<<(512 * 56 + 255) / 256, 256, 0, stream>>>(Wb, WREG);
    k_packAl<<<(512 * 72 + 255) / 256, 256, 0, stream>>>(Wb, WLDS);

    k_xg<<<SEQ, 1024, 0, stream>>>(text, wordvector, WihL, bihL, bhhL, XGF);
    k_xg<<<SEQ, 1024, 0, stream>>>(text, wordvector, WihR, bihR, bhhR, XGB);
    k_lstm<<<2, 1024, 0, stream>>>(XGF, XGB, WHLT, WHRT, WORDIN);
    k_prep2<<<SEQ + NREL + NENT, 256, 0, stream>>>(WORDIN, WTWT, WBWT, WTRT, WBET,
                                                   relvec, entvec, bt, bb,
                                                   TW, BW, RVb, EVb);
    k_mainA<<<1, 512, 0, stream>>>(TW, BW, RVb, EVb, WTMT, WTBT, WBTT, M1T, C1,
                                   WREG, WLDS, Wp, bp, Wpl, bpl, btb, bbt,
                                   (float*)d_out);
}